// Round 18
// baseline (72.958 us; speedup 1.0000x reference)
//
#include <hip/hip_runtime.h>
#include <hip/hip_bf16.h>

typedef __bf16 bf16x8 __attribute__((ext_vector_type(8)));
typedef __bf16 bf16x4 __attribute__((ext_vector_type(4)));
typedef float  f32x4  __attribute__((ext_vector_type(4)));

constexpr int BATCH = 2, H = 8, NQ = 1024, SEQ = 8192, DIM = 256, HD = 32;
constexpr int CHUNKS = 8, KVCHUNK = SEQ / CHUNKS;   // 8 x 1024 (16 chunks was net-worse: partial traffic, round 11)
constexpr float SCALE = 0.17677669529663687f;   // 32^-0.5
constexpr float LOG2E = 1.4426950408889634f;
constexpr float QSCALE = SCALE * LOG2E;         // fold log2(e): softmax in exp2 domain
constexpr float MASKC = 100.0f * LOG2E;
constexpr float MFIX  = 12.0f;                  // fixed softmax max (scores ~N(0,1.44) exp2-domain, gmax~8.5)

// workspace layout (bytes)
constexpr size_t OFF_QH   = 0;                                      // bf16 [B*H][NQ][32]
constexpr size_t OFF_KH   = OFF_QH  + (size_t)BATCH*H*NQ*HD*2;      // bf16 [B*H][S][32]
constexpr size_t OFF_VT   = OFF_KH  + (size_t)BATCH*H*SEQ*HD*2;     // bf16 [B*H][32][S]
constexpr size_t OFF_CTX  = OFF_VT  + (size_t)BATCH*H*SEQ*HD*2;     // f32  [B*NQ][256]
constexpr size_t OFF_W    = OFF_CTX + (size_t)BATCH*NQ*DIM*4;       // bf16 4 x [256][256]
constexpr size_t OFF_PL   = OFF_W   + (size_t)4*DIM*DIM*2;          // f32 [CHUNKS][16][NQ]
constexpr size_t OFF_BIAS = OFF_PL  + (size_t)CHUNKS*16*NQ*4;       // f32 [B][S]
constexpr size_t OFF_PO   = OFF_BIAS + (size_t)BATCH*SEQ*4;         // f32 [CHUNKS][16][NQ][32]

// Compiler-visible exp2 (v_exp_f32). NOT inline asm: hipcc must see the MFMA->TRANS
// dependency to insert the MFMA-dest read hazard slots (inline-asm consumer of a raw
// MFMA result read garbage -> inf -> NaN in rounds 4/5/8).
__device__ __forceinline__ float fast_exp2(float x) {
    return __builtin_amdgcn_exp2f(x);
}

__global__ void prep_weights_kernel(const float* __restrict__ Wq, const float* __restrict__ Wk,
                                    const float* __restrict__ Wv, const float* __restrict__ Wo,
                                    const float* __restrict__ mask,
                                    __bf16* __restrict__ out, float* __restrict__ biasv) {
    int i = blockIdx.x * 256 + threadIdx.x;          // 65536 threads
    out[i]          = (__bf16)(Wq[i] * QSCALE);      // fold q-scale * log2e into Wq
    out[65536 + i]  = (__bf16)(Wk[i]);
    out[131072 + i] = (__bf16)(Wv[i]);
    out[196608 + i] = (__bf16)(Wo[i]);
    if (i < BATCH * SEQ)
        biasv[i] = -(mask[i] * MASKC + MFIX);        // folded into QK^T C-operand
}

// Fused Q/K/V projection, tile 64 rows x 128 cols, BK=64.
// 64x128 -> grid 1088 = 4.25 blocks/CU, LDS 27.7KB, per-wave 32x64 (acc[2][4]).
// Blocks: Q:64, K:512, V:512. mode 0: head layout [b*H+h][row][hd];
// mode 1: V^T [b*H+h][hd][row] (MFMA operands swapped).
__global__ __launch_bounds__(256, 2)
void qkv_proj_kernel(const float* __restrict__ Xq, const float* __restrict__ Xk,
                     const float* __restrict__ Xv, const __bf16* __restrict__ Wb,
                     const float* __restrict__ bq, const float* __restrict__ bk,
                     const float* __restrict__ bv,
                     __bf16* __restrict__ qh, __bf16* __restrict__ kh, __bf16* __restrict__ vtp)
{
    __shared__ __bf16 Ash[64][72];    // 64 rows x 64 k (+8 pad; stride 144B = 9x16 aligned)
    __shared__ __bf16 Bsh[128][72];   // 128 n  x 64 k (+8 pad)
    const int bid = blockIdx.x;
    const float* X; const __bf16* W; const float* bias; float bscale;
    __bf16* outp; int Mb, mode, lbid;
    if (bid < 64)       { X = Xq; W = Wb;          bias = bq; bscale = QSCALE; outp = qh;  Mb = NQ;  mode = 0; lbid = bid; }
    else if (bid < 576) { X = Xk; W = Wb + 65536;  bias = bk; bscale = 1.f;    outp = kh;  Mb = SEQ; mode = 0; lbid = bid - 64; }
    else                { X = Xv; W = Wb + 131072; bias = bv; bscale = 1.f;    outp = vtp; Mb = SEQ; mode = 1; lbid = bid - 576; }

    const int m0 = (lbid >> 1) * 64;
    const int n0 = (lbid & 1) * 128;
    const int t = threadIdx.x;
    const int w = t >> 6;
    const int lane = t & 63;
    const int g = lane >> 4;
    const int lr = lane & 15;
    const int wr = w >> 1, wc = w & 1;   // wave: rows wr*32..+32, cols wc*64..+64

    f32x4 acc[2][4] = {};

    for (int kk = 0; kk < DIM; kk += 64) {
        __syncthreads();
        // stage A: 64x64 fp32 -> bf16 (1024 float4 chunks, 4/thread)
        #pragma unroll
        for (int i = 0; i < 4; ++i) {
            int c = i * 256 + t;
            int row = c >> 4;
            int q = c & 15;
            const float4 v = *reinterpret_cast<const float4*>(X + (size_t)(m0 + row) * DIM + kk + q * 4);
            bf16x4 bvv;
            bvv[0] = (__bf16)v.x; bvv[1] = (__bf16)v.y; bvv[2] = (__bf16)v.z; bvv[3] = (__bf16)v.w;
            *reinterpret_cast<bf16x4*>(&Ash[row][q * 4]) = bvv;
        }
        // stage B: 128x64 bf16 (1024 8-elem chunks, 4/thread)
        #pragma unroll
        for (int i = 0; i < 4; ++i) {
            int c = i * 256 + t;
            int row = c >> 3;
            int q = c & 7;
            *reinterpret_cast<bf16x8*>(&Bsh[row][q * 8]) =
                *reinterpret_cast<const bf16x8*>(W + (size_t)(n0 + row) * DIM + kk + q * 8);
        }
        __syncthreads();

        #pragma unroll
        for (int ks = 0; ks < 2; ++ks) {
            bf16x8 af[2], bfr[4];
            #pragma unroll
            for (int mt = 0; mt < 2; ++mt)
                af[mt] = *reinterpret_cast<const bf16x8*>(&Ash[wr * 32 + mt * 16 + lr][ks * 32 + g * 8]);
            #pragma unroll
            for (int nt = 0; nt < 4; ++nt)
                bfr[nt] = *reinterpret_cast<const bf16x8*>(&Bsh[wc * 64 + nt * 16 + lr][ks * 32 + g * 8]);
            if (mode == 1) {
                #pragma unroll
                for (int mt = 0; mt < 2; ++mt)
                    #pragma unroll
                    for (int nt = 0; nt < 4; ++nt)
                        acc[mt][nt] = __builtin_amdgcn_mfma_f32_16x16x32_bf16(bfr[nt], af[mt], acc[mt][nt], 0, 0, 0);
            } else {
                #pragma unroll
                for (int mt = 0; mt < 2; ++mt)
                    #pragma unroll
                    for (int nt = 0; nt < 4; ++nt)
                        acc[mt][nt] = __builtin_amdgcn_mfma_f32_16x16x32_bf16(af[mt], bfr[nt], acc[mt][nt], 0, 0, 0);
            }
        }
    }

    const int bb = m0 / Mb;            // whole tile lies in one batch (64 | Mb)
    const int sbase = m0 - bb * Mb + wr * 32;

    if (mode == 0) {
        #pragma unroll
        for (int nt = 0; nt < 4; ++nt) {
            int n = n0 + wc * 64 + nt * 16 + lr;
            float bvv = bias[n] * bscale;
            int h = n >> 5, hd = n & 31;
            __bf16* op = outp + ((size_t)(bb * H + h) * Mb) * 32 + hd;
            #pragma unroll
            for (int mt = 0; mt < 2; ++mt)
                #pragma unroll
                for (int r = 0; r < 4; ++r) {
                    int s = sbase + mt * 16 + g * 4 + r;
                    op[(size_t)s * 32] = (__bf16)(acc[mt][nt][r] + bvv);
                }
        }
    } else {
        #pragma unroll
        for (int nt = 0; nt < 4; ++nt)
            #pragma unroll
            for (int r = 0; r < 4; ++r) {
                int n = n0 + wc * 64 + nt * 16 + g * 4 + r;   // D rows = n (operands swapped)
                float bvv = bias[n] * bscale;
                int h = n >> 5, hd = n & 31;
                __bf16* op = outp + ((size_t)(bb * H + h) * 32 + hd) * SEQ;
                #pragma unroll
                for (int mt = 0; mt < 2; ++mt) {
                    int s = sbase + mt * 16 + lr;             // D cols = m (contiguous per 16 lanes)
                    op[s] = (__bf16)(acc[mt][nt][r] + bvv);
                }
            }
    }
}

// O-projection 64x64 tiles (grid 128). 4 waves, each 32x32 (acc[2][2]).
__global__ __launch_bounds__(256, 2)
void oproj_kernel(const float* __restrict__ X, const __bf16* __restrict__ W,
                  const float* __restrict__ bias, float* __restrict__ outf)
{
    __shared__ __bf16 Ash[64][72];
    __shared__ __bf16 Bsh[64][72];
    const int m0 = (blockIdx.x >> 2) * 64;
    const int n0 = (blockIdx.x & 3) * 64;
    const int t = threadIdx.x;
    const int w = t >> 6;
    const int lane = t & 63;
    const int g = lane >> 4;
    const int lr = lane & 15;
    const int wr = w >> 1, wc = w & 1;

    f32x4 acc[2][2] = {};

    for (int kk = 0; kk < DIM; kk += 64) {
        __syncthreads();
        #pragma unroll
        for (int i = 0; i < 4; ++i) {
            int c = i * 256 + t;
            int row = c >> 4;
            int q = c & 15;
            const float4 v = *reinterpret_cast<const float4*>(X + (size_t)(m0 + row) * DIM + kk + q * 4);
            bf16x4 bvv;
            bvv[0] = (__bf16)v.x; bvv[1] = (__bf16)v.y; bvv[2] = (__bf16)v.z; bvv[3] = (__bf16)v.w;
            *reinterpret_cast<bf16x4*>(&Ash[row][q * 4]) = bvv;
        }
        #pragma unroll
        for (int i = 0; i < 2; ++i) {
            int c = i * 256 + t;
            int row = c >> 3;
            int q = c & 7;
            *reinterpret_cast<bf16x8*>(&Bsh[row][q * 8]) =
                *reinterpret_cast<const bf16x8*>(W + (size_t)(n0 + row) * DIM + kk + q * 8);
        }
        __syncthreads();

        #pragma unroll
        for (int ks = 0; ks < 2; ++ks) {
            bf16x8 af[2], bfr[2];
            #pragma unroll
            for (int mt = 0; mt < 2; ++mt)
                af[mt] = *reinterpret_cast<const bf16x8*>(&Ash[wr * 32 + mt * 16 + lr][ks * 32 + g * 8]);
            #pragma unroll
            for (int nt = 0; nt < 2; ++nt)
                bfr[nt] = *reinterpret_cast<const bf16x8*>(&Bsh[wc * 32 + nt * 16 + lr][ks * 32 + g * 8]);
            #pragma unroll
            for (int mt = 0; mt < 2; ++mt)
                #pragma unroll
                for (int nt = 0; nt < 2; ++nt)
                    acc[mt][nt] = __builtin_amdgcn_mfma_f32_16x16x32_bf16(af[mt], bfr[nt], acc[mt][nt], 0, 0, 0);
        }
    }

    #pragma unroll
    for (int nt = 0; nt < 2; ++nt) {
        int n = n0 + wc * 32 + nt * 16 + lr;
        float bvv = bias[n];
        #pragma unroll
        for (int mt = 0; mt < 2; ++mt)
            #pragma unroll
            for (int r = 0; r < 4; ++r) {
                int m = m0 + wr * 32 + mt * 16 + g * 4 + r;
                outf[(size_t)m * DIM + n] = acc[mt][nt][r] + bvv;
            }
    }
}

// Flash attention: 256 threads, 4 waves, 2 qi/wave, single LDS buffer,
// KVTILE=128 processed as two sequential 64-halves inside ONE barrier pair
// (halves barrier count 32->16 and doubles per-barrier MFMA work; round-14's
// lesson in reverse). Issue-early staging regs retained.
// FIXED-MAX softmax, mask+MFIX bias via QK^T C-operand, l via ones-row MFMA.
// Grid 1024 = 16 bh x 8 q-tiles(128 rows) x 8 kv-chunks(1024). launch_bounds(256,4).
__global__ __launch_bounds__(256, 4)
void attn_kernel(const __bf16* __restrict__ qh, const __bf16* __restrict__ kh,
                 const __bf16* __restrict__ vt, const float* __restrict__ biasv,
                 float* __restrict__ Pl, float* __restrict__ Po)
{
    __shared__ __bf16 Ksh[128][40];   // kv-rows x 32 hd (+8 pad; stride 80B)
    __shared__ __bf16 Vsh[32][136];   // hd-rows x 128 kv (+8 pad; stride 272B = 17x16 aligned)

    const int bid = blockIdx.x;
    const int bh = bid & 15;
    const int qt = (bid >> 4) & 7;
    const int ck = bid >> 7;                 // 0..7
    const int b = bh >> 3;
    const int t = threadIdx.x;
    const int w = t >> 6, lane = t & 63, g = lane >> 4, lr = lane & 15;
    const int q0 = qt * 128 + w * 32;

    bf16x8 qf[2];
    #pragma unroll
    for (int qi = 0; qi < 2; ++qi)
        qf[qi] = *reinterpret_cast<const bf16x8*>(qh + ((size_t)bh * NQ + q0 + qi * 16 + lr) * HD + g * 8);

    const __bf16* kb = kh + (size_t)bh * SEQ * HD;
    const __bf16* vb = vt + (size_t)bh * HD * SEQ;
    const float* bvp = biasv + (size_t)b * SEQ;

    bf16x8 ones;
    #pragma unroll
    for (int i = 0; i < 8; ++i) ones[i] = (__bf16)1.0f;

    // staging indices for 128-kv tile (256 threads x 2 chunks of 16B for K and V each)
    // K: 128 rows x 32 hd = 512 chunks; c = i*256+t; row = c>>2, col = (c&3)*8
    // V: 32 rows x 128 kv = 512 chunks; c = i*256+t; row = c>>4, col = (c&15)*8
    const int kr0 = t >> 2, kc0 = (t & 3) * 8;
    const int kr1 = (256 + t) >> 2, kc1 = ((256 + t) & 3) * 8;
    const int vr0 = t >> 4, vc0 = (t & 15) * 8;
    const int vr1 = (256 + t) >> 4, vc1 = ((256 + t) & 15) * 8;

    const int kv0 = ck * KVCHUNK;
    const int kvend = kv0 + KVCHUNK;
    f32x4 o[2][2] = {};
    f32x4 l_acc[2] = {};

    // prologue: load tile 0 into regs
    bf16x8 kreg0 = *reinterpret_cast<const bf16x8*>(kb + (size_t)(kv0 + kr0) * HD + kc0);
    bf16x8 kreg1 = *reinterpret_cast<const bf16x8*>(kb + (size_t)(kv0 + kr1) * HD + kc1);
    bf16x8 vreg0 = *reinterpret_cast<const bf16x8*>(vb + (size_t)vr0 * SEQ + kv0 + vc0);
    bf16x8 vreg1 = *reinterpret_cast<const bf16x8*>(vb + (size_t)vr1 * SEQ + kv0 + vc1);

    for (int kv = kv0; kv < kvend; kv += 128) {
        __syncthreads();      // previous tile's LDS reads complete
        *reinterpret_cast<bf16x8*>(&Ksh[kr0][kc0]) = kreg0;
        *reinterpret_cast<bf16x8*>(&Ksh[kr1][kc1]) = kreg1;
        *reinterpret_cast<bf16x8*>(&Vsh[vr0][vc0]) = vreg0;
        *reinterpret_cast<bf16x8*>(&Vsh[vr1][vc1]) = vreg1;
        // issue next tile's loads NOW: latency overlaps this tile's compute
        if (kv + 128 < kvend) {
            kreg0 = *reinterpret_cast<const bf16x8*>(kb + (size_t)(kv + 128 + kr0) * HD + kc0);
            kreg1 = *reinterpret_cast<const bf16x8*>(kb + (size_t)(kv + 128 + kr1) * HD + kc1);
            vreg0 = *reinterpret_cast<const bf16x8*>(vb + (size_t)vr0 * SEQ + kv + 128 + vc0);
            vreg1 = *reinterpret_cast<const bf16x8*>(vb + (size_t)vr1 * SEQ + kv + 128 + vc1);
        }
        __syncthreads();      // this tile's LDS writes visible

        #pragma unroll
        for (int half = 0; half < 2; ++half) {
            const int hrow = half * 64;

            bf16x8 kf[4];
            #pragma unroll
            for (int j = 0; j < 4; ++j)
                kf[j] = *reinterpret_cast<const bf16x8*>(&Ksh[hrow + j * 16 + lr][g * 8]);

            bf16x4 vraw[2][4];
            #pragma unroll
            for (int hf = 0; hf < 2; ++hf)
                #pragma unroll
                for (int j = 0; j < 4; ++j)
                    vraw[hf][j] = *reinterpret_cast<const bf16x4*>(&Vsh[hf * 16 + lr][hrow + j * 16 + g * 4]);
            bf16x8 vf[2][2];
            #pragma unroll
            for (int hf = 0; hf < 2; ++hf) {
                vf[hf][0] = __builtin_shufflevector(vraw[hf][0], vraw[hf][1], 0, 1, 2, 3, 4, 5, 6, 7);
                vf[hf][1] = __builtin_shufflevector(vraw[hf][2], vraw[hf][3], 0, 1, 2, 3, 4, 5, 6, 7);
            }

            // bias (-mask*MASKC - MFIX) as QK^T C-operand: C row = kv position
            f32x4 bc[4];
            #pragma unroll
            for (int j = 0; j < 4; ++j) {
                const float4 m4 = *reinterpret_cast<const float4*>(bvp + kv + hrow + j * 16 + g * 4);
                bc[j][0] = m4.x; bc[j][1] = m4.y; bc[j][2] = m4.z; bc[j][3] = m4.w;
            }

            #pragma unroll
            for (int qi = 0; qi < 2; ++qi) {
                f32x4 s[4];
                #pragma unroll
                for (int j = 0; j < 4; ++j)
                    s[j] = __builtin_amdgcn_mfma_f32_16x16x32_bf16(kf[j], qf[qi], bc[j], 0, 0, 0);

                // fixed-max softmax: p = 2^(qk + bias); masked -> 2^(-156) = exact 0
                float p[16];
                #pragma unroll
                for (int j = 0; j < 4; ++j)
                    #pragma unroll
                    for (int r = 0; r < 4; ++r)
                        p[j * 4 + r] = fast_exp2(s[j][r]);

                bf16x8 pf0, pf1;
                #pragma unroll
                for (int i = 0; i < 8; ++i) { pf0[i] = (__bf16)p[i]; pf1[i] = (__bf16)p[8 + i]; }

                o[qi][0] = __builtin_amdgcn_mfma_f32_16x16x32_bf16(vf[0][0], pf0, o[qi][0], 0, 0, 0);
                o[qi][0] = __builtin_amdgcn_mfma_f32_16x16x32_bf16(vf[0][1], pf1, o[qi][0], 0, 0, 0);
                o[qi][1] = __builtin_amdgcn_mfma_f32_16x16x32_bf16(vf[1][0], pf0, o[qi][1], 0, 0, 0);
                o[qi][1] = __builtin_amdgcn_mfma_f32_16x16x32_bf16(vf[1][1], pf1, o[qi][1], 0, 0, 0);
                // l = sum_k P[k][q] via ones-row MFMA: D[m][q] identical over m; read reg 0 at g==0
                l_acc[qi] = __builtin_amdgcn_mfma_f32_16x16x32_bf16(ones, pf0, l_acc[qi], 0, 0, 0);
                l_acc[qi] = __builtin_amdgcn_mfma_f32_16x16x32_bf16(ones, pf1, l_acc[qi], 0, 0, 0);
            }
        }
    }

    // write unnormalized partials (fixed max -> no m needed)
    #pragma unroll
    for (int qi = 0; qi < 2; ++qi) {
        const int row = q0 + qi * 16 + lr;
        const size_t base = ((size_t)ck * 16 + bh) * NQ + row;
        if (g == 0) Pl[base] = l_acc[qi][0];
        #pragma unroll
        for (int hf = 0; hf < 2; ++hf)
            *reinterpret_cast<f32x4*>(Po + base * 32 + hf * 16 + g * 4) = o[qi][hf];
    }
}

// Merge split-K partials (shared fixed max): ctx = sum_c o_c / sum_c l_c
__global__ __launch_bounds__(256)
void combine_kernel(const float* __restrict__ Pl, const float* __restrict__ Po,
                    float* __restrict__ ctx)
{
    const int idx = blockIdx.x * 256 + threadIdx.x;   // 16*1024*32
    const int hd = idx & 31;
    const int row = (idx >> 5) & (NQ - 1);
    const int bh = idx >> 15;
    const int b = bh >> 3, h = bh & 7;

    float lsum = 0.f, osum = 0.f;
    #pragma unroll
    for (int c = 0; c < CHUNKS; ++c) {
        const size_t base = ((size_t)c * 16 + bh) * NQ + row;
        lsum += Pl[base];
        osum += Po[base * 32 + hd];
    }
    ctx[((size_t)b * NQ + row) * DIM + h * HD + hd] = osum / lsum;
}

extern "C" void kernel_launch(void* const* d_in, const int* in_sizes, int n_in,
                              void* d_out, int out_size, void* d_ws, size_t ws_size,
                              hipStream_t stream)
{
    const float* Xq   = (const float*)d_in[0];
    const float* Xk   = (const float*)d_in[1];
    const float* Xv   = (const float*)d_in[2];
    const float* mask = (const float*)d_in[3];
    const float* Wq   = (const float*)d_in[4];
    const float* bq   = (const float*)d_in[5];
    const float* Wk   = (const float*)d_in[6];
    const float* bk   = (const float*)d_in[7];
    const float* Wv   = (const float*)d_in[8];
    const float* bv   = (const float*)d_in[9];
    const float* Wo   = (const float*)d_in[10];
    const float* bo   = (const float*)d_in[11];

    char* ws = (char*)d_ws;
    __bf16* qh  = (__bf16*)(ws + OFF_QH);
    __bf16* kh  = (__bf16*)(ws + OFF_KH);
    __bf16* vtp = (__bf16*)(ws + OFF_VT);
    float*  ctx = (float*)(ws + OFF_CTX);
    __bf16* Wb  = (__bf16*)(ws + OFF_W);
    float*  Pl  = (float*)(ws + OFF_PL);
    float*  biasv = (float*)(ws + OFF_BIAS);
    float*  Po  = (float*)(ws + OFF_PO);

    prep_weights_kernel<<<256, 256, 0, stream>>>(Wq, Wk, Wv, Wo, mask, Wb, biasv);
    qkv_proj_kernel<<<1088, 256, 0, stream>>>(Xq, Xk, Xv, Wb, bq, bk, bv, qh, kh, vtp);
    attn_kernel<<<16 * 8 * CHUNKS, 256, 0, stream>>>(qh, kh, vtp, biasv, Pl, Po);
    combine_kernel<<<16 * NQ * 32 / 256, 256, 0, stream>>>(Pl, Po, ctx);
    oproj_kernel<<<128, 256, 0, stream>>>(ctx, Wb + 196608, bo, (float*)d_out);
}

// Round 19
// 65.390 us; speedup vs baseline: 1.1157x; 1.1157x over previous
//
#include <hip/hip_runtime.h>
#include <hip/hip_bf16.h>

typedef __bf16 bf16x8 __attribute__((ext_vector_type(8)));
typedef __bf16 bf16x4 __attribute__((ext_vector_type(4)));
typedef float  f32x4  __attribute__((ext_vector_type(4)));

constexpr int BATCH = 2, H = 8, NQ = 1024, SEQ = 8192, DIM = 256, HD = 32;
constexpr int CHUNKS = 8, KVCHUNK = SEQ / CHUNKS;   // 8 x 1024 (16 chunks was net-worse: partial traffic, round 11)
constexpr float SCALE = 0.17677669529663687f;   // 32^-0.5
constexpr float LOG2E = 1.4426950408889634f;
constexpr float QSCALE = SCALE * LOG2E;         // fold log2(e): softmax in exp2 domain
constexpr float MASKC = 100.0f * LOG2E;
constexpr float MFIX  = 12.0f;                  // fixed softmax max (scores ~N(0,1.44) exp2-domain, gmax~8.5)

// workspace layout (bytes)
constexpr size_t OFF_QH   = 0;                                      // bf16 [B*H][NQ][32]
constexpr size_t OFF_KH   = OFF_QH  + (size_t)BATCH*H*NQ*HD*2;      // bf16 [B*H][S][32]
constexpr size_t OFF_VT   = OFF_KH  + (size_t)BATCH*H*SEQ*HD*2;     // bf16 [B*H][32][S]
constexpr size_t OFF_CTX  = OFF_VT  + (size_t)BATCH*H*SEQ*HD*2;     // bf16 [B*NQ][256] (was f32; bf16 = same rounding point as oproj's old A-stage cvt)
constexpr size_t OFF_W    = OFF_CTX + (size_t)BATCH*NQ*DIM*4;       // bf16 4 x [256][256]
constexpr size_t OFF_PL   = OFF_W   + (size_t)4*DIM*DIM*2;          // f32 [CHUNKS][16][NQ]
constexpr size_t OFF_BIAS = OFF_PL  + (size_t)CHUNKS*16*NQ*4;       // f32 [B][S]
constexpr size_t OFF_PO   = OFF_BIAS + (size_t)BATCH*SEQ*4;         // f32 [CHUNKS][16][NQ][32]

// Compiler-visible exp2 (v_exp_f32). NOT inline asm: hipcc must see the MFMA->TRANS
// dependency to insert the MFMA-dest read hazard slots (inline-asm consumer of a raw
// MFMA result read garbage -> inf -> NaN in rounds 4/5/8).
__device__ __forceinline__ float fast_exp2(float x) {
    return __builtin_amdgcn_exp2f(x);
}

__global__ void prep_weights_kernel(const float* __restrict__ Wq, const float* __restrict__ Wk,
                                    const float* __restrict__ Wv, const float* __restrict__ Wo,
                                    const float* __restrict__ mask,
                                    __bf16* __restrict__ out, float* __restrict__ biasv) {
    int i = blockIdx.x * 256 + threadIdx.x;          // 65536 threads
    out[i]          = (__bf16)(Wq[i] * QSCALE);      // fold q-scale * log2e into Wq
    out[65536 + i]  = (__bf16)(Wk[i]);
    out[131072 + i] = (__bf16)(Wv[i]);
    out[196608 + i] = (__bf16)(Wo[i]);
    if (i < BATCH * SEQ)
        biasv[i] = -(mask[i] * MASKC + MFIX);        // folded into QK^T C-operand
}

// Fused Q/K/V projection, tile 64 rows x 128 cols, BK=64.
// 64x128 -> grid 1088 = 4.25 blocks/CU, LDS 27.7KB, per-wave 32x64 (acc[2][4]).
// Blocks: Q:64, K:512, V:512. mode 0: head layout [b*H+h][row][hd];
// mode 1: V^T [b*H+h][hd][row] (MFMA operands swapped).
__global__ __launch_bounds__(256, 2)
void qkv_proj_kernel(const float* __restrict__ Xq, const float* __restrict__ Xk,
                     const float* __restrict__ Xv, const __bf16* __restrict__ Wb,
                     const float* __restrict__ bq, const float* __restrict__ bk,
                     const float* __restrict__ bv,
                     __bf16* __restrict__ qh, __bf16* __restrict__ kh, __bf16* __restrict__ vtp)
{
    __shared__ __bf16 Ash[64][72];    // 64 rows x 64 k (+8 pad; stride 144B = 9x16 aligned)
    __shared__ __bf16 Bsh[128][72];   // 128 n  x 64 k (+8 pad)
    const int bid = blockIdx.x;
    const float* X; const __bf16* W; const float* bias; float bscale;
    __bf16* outp; int Mb, mode, lbid;
    if (bid < 64)       { X = Xq; W = Wb;          bias = bq; bscale = QSCALE; outp = qh;  Mb = NQ;  mode = 0; lbid = bid; }
    else if (bid < 576) { X = Xk; W = Wb + 65536;  bias = bk; bscale = 1.f;    outp = kh;  Mb = SEQ; mode = 0; lbid = bid - 64; }
    else                { X = Xv; W = Wb + 131072; bias = bv; bscale = 1.f;    outp = vtp; Mb = SEQ; mode = 1; lbid = bid - 576; }

    const int m0 = (lbid >> 1) * 64;
    const int n0 = (lbid & 1) * 128;
    const int t = threadIdx.x;
    const int w = t >> 6;
    const int lane = t & 63;
    const int g = lane >> 4;
    const int lr = lane & 15;
    const int wr = w >> 1, wc = w & 1;   // wave: rows wr*32..+32, cols wc*64..+64

    f32x4 acc[2][4] = {};

    for (int kk = 0; kk < DIM; kk += 64) {
        __syncthreads();
        // stage A: 64x64 fp32 -> bf16 (1024 float4 chunks, 4/thread)
        #pragma unroll
        for (int i = 0; i < 4; ++i) {
            int c = i * 256 + t;
            int row = c >> 4;
            int q = c & 15;
            const float4 v = *reinterpret_cast<const float4*>(X + (size_t)(m0 + row) * DIM + kk + q * 4);
            bf16x4 bvv;
            bvv[0] = (__bf16)v.x; bvv[1] = (__bf16)v.y; bvv[2] = (__bf16)v.z; bvv[3] = (__bf16)v.w;
            *reinterpret_cast<bf16x4*>(&Ash[row][q * 4]) = bvv;
        }
        // stage B: 128x64 bf16 (1024 8-elem chunks, 4/thread)
        #pragma unroll
        for (int i = 0; i < 4; ++i) {
            int c = i * 256 + t;
            int row = c >> 3;
            int q = c & 7;
            *reinterpret_cast<bf16x8*>(&Bsh[row][q * 8]) =
                *reinterpret_cast<const bf16x8*>(W + (size_t)(n0 + row) * DIM + kk + q * 8);
        }
        __syncthreads();

        #pragma unroll
        for (int ks = 0; ks < 2; ++ks) {
            bf16x8 af[2], bfr[4];
            #pragma unroll
            for (int mt = 0; mt < 2; ++mt)
                af[mt] = *reinterpret_cast<const bf16x8*>(&Ash[wr * 32 + mt * 16 + lr][ks * 32 + g * 8]);
            #pragma unroll
            for (int nt = 0; nt < 4; ++nt)
                bfr[nt] = *reinterpret_cast<const bf16x8*>(&Bsh[wc * 64 + nt * 16 + lr][ks * 32 + g * 8]);
            if (mode == 1) {
                #pragma unroll
                for (int mt = 0; mt < 2; ++mt)
                    #pragma unroll
                    for (int nt = 0; nt < 4; ++nt)
                        acc[mt][nt] = __builtin_amdgcn_mfma_f32_16x16x32_bf16(bfr[nt], af[mt], acc[mt][nt], 0, 0, 0);
            } else {
                #pragma unroll
                for (int mt = 0; mt < 2; ++mt)
                    #pragma unroll
                    for (int nt = 0; nt < 4; ++nt)
                        acc[mt][nt] = __builtin_amdgcn_mfma_f32_16x16x32_bf16(af[mt], bfr[nt], acc[mt][nt], 0, 0, 0);
            }
        }
    }

    const int bb = m0 / Mb;            // whole tile lies in one batch (64 | Mb)
    const int sbase = m0 - bb * Mb + wr * 32;

    if (mode == 0) {
        #pragma unroll
        for (int nt = 0; nt < 4; ++nt) {
            int n = n0 + wc * 64 + nt * 16 + lr;
            float bvv = bias[n] * bscale;
            int h = n >> 5, hd = n & 31;
            __bf16* op = outp + ((size_t)(bb * H + h) * Mb) * 32 + hd;
            #pragma unroll
            for (int mt = 0; mt < 2; ++mt)
                #pragma unroll
                for (int r = 0; r < 4; ++r) {
                    int s = sbase + mt * 16 + g * 4 + r;
                    op[(size_t)s * 32] = (__bf16)(acc[mt][nt][r] + bvv);
                }
        }
    } else {
        #pragma unroll
        for (int nt = 0; nt < 4; ++nt)
            #pragma unroll
            for (int r = 0; r < 4; ++r) {
                int n = n0 + wc * 64 + nt * 16 + g * 4 + r;   // D rows = n (operands swapped)
                float bvv = bias[n] * bscale;
                int h = n >> 5, hd = n & 31;
                __bf16* op = outp + ((size_t)(bb * H + h) * 32 + hd) * SEQ;
                #pragma unroll
                for (int mt = 0; mt < 2; ++mt) {
                    int s = sbase + mt * 16 + lr;             // D cols = m (contiguous per 16 lanes)
                    op[s] = (__bf16)(acc[mt][nt][r] + bvv);
                }
            }
    }
}

// O-projection 64x64 tiles (grid 128). 4 waves, each 32x32 (acc[2][2]).
// X (ctx) is now bf16: stage A is a straight bf16 copy (cvt moved into combine — identical rounding).
__global__ __launch_bounds__(256, 2)
void oproj_kernel(const __bf16* __restrict__ X, const __bf16* __restrict__ W,
                  const float* __restrict__ bias, float* __restrict__ outf)
{
    __shared__ __bf16 Ash[64][72];
    __shared__ __bf16 Bsh[64][72];
    const int m0 = (blockIdx.x >> 2) * 64;
    const int n0 = (blockIdx.x & 3) * 64;
    const int t = threadIdx.x;
    const int w = t >> 6;
    const int lane = t & 63;
    const int g = lane >> 4;
    const int lr = lane & 15;
    const int wr = w >> 1, wc = w & 1;

    f32x4 acc[2][2] = {};

    for (int kk = 0; kk < DIM; kk += 64) {
        __syncthreads();
        // stage A: 64x64 bf16 copy (512 chunks, 2/thread)
        #pragma unroll
        for (int i = 0; i < 2; ++i) {
            int c = i * 256 + t;
            int row = c >> 3;
            int q = c & 7;
            *reinterpret_cast<bf16x8*>(&Ash[row][q * 8]) =
                *reinterpret_cast<const bf16x8*>(X + (size_t)(m0 + row) * DIM + kk + q * 8);
        }
        // stage B: 64x64 bf16 (512 chunks, 2/thread)
        #pragma unroll
        for (int i = 0; i < 2; ++i) {
            int c = i * 256 + t;
            int row = c >> 3;
            int q = c & 7;
            *reinterpret_cast<bf16x8*>(&Bsh[row][q * 8]) =
                *reinterpret_cast<const bf16x8*>(W + (size_t)(n0 + row) * DIM + kk + q * 8);
        }
        __syncthreads();

        #pragma unroll
        for (int ks = 0; ks < 2; ++ks) {
            bf16x8 af[2], bfr[2];
            #pragma unroll
            for (int mt = 0; mt < 2; ++mt)
                af[mt] = *reinterpret_cast<const bf16x8*>(&Ash[wr * 32 + mt * 16 + lr][ks * 32 + g * 8]);
            #pragma unroll
            for (int nt = 0; nt < 2; ++nt)
                bfr[nt] = *reinterpret_cast<const bf16x8*>(&Bsh[wc * 32 + nt * 16 + lr][ks * 32 + g * 8]);
            #pragma unroll
            for (int mt = 0; mt < 2; ++mt)
                #pragma unroll
                for (int nt = 0; nt < 2; ++nt)
                    acc[mt][nt] = __builtin_amdgcn_mfma_f32_16x16x32_bf16(af[mt], bfr[nt], acc[mt][nt], 0, 0, 0);
        }
    }

    #pragma unroll
    for (int nt = 0; nt < 2; ++nt) {
        int n = n0 + wc * 32 + nt * 16 + lr;
        float bvv = bias[n];
        #pragma unroll
        for (int mt = 0; mt < 2; ++mt)
            #pragma unroll
            for (int r = 0; r < 4; ++r) {
                int m = m0 + wr * 32 + mt * 16 + g * 4 + r;
                outf[(size_t)m * DIM + n] = acc[mt][nt][r] + bvv;
            }
    }
}

// Flash attention (round-16 best config: 256 threads, 4 waves, 2 qi/wave, single LDS
// buffer, KVTILE=64, issue-early staging). FIXED-MAX softmax, mask+MFIX bias via
// QK^T C-operand, l via ones-row MFMA.
// Grid 1024 = 16 bh x 8 q-tiles(128 rows) x 8 kv-chunks(1024). launch_bounds(256,4).
__global__ __launch_bounds__(256, 4)
void attn_kernel(const __bf16* __restrict__ qh, const __bf16* __restrict__ kh,
                 const __bf16* __restrict__ vt, const float* __restrict__ biasv,
                 float* __restrict__ Pl, float* __restrict__ Po)
{
    __shared__ __bf16 Ksh[64][40];    // kv-rows x 32 hd (+8 pad)
    __shared__ __bf16 Vsh[32][72];    // hd-rows x 64 kv (+8 pad; stride 144B = 9x16 aligned)

    const int bid = blockIdx.x;
    const int bh = bid & 15;
    const int qt = (bid >> 4) & 7;
    const int ck = bid >> 7;                 // 0..7
    const int b = bh >> 3;
    const int t = threadIdx.x;
    const int w = t >> 6, lane = t & 63, g = lane >> 4, lr = lane & 15;
    const int q0 = qt * 128 + w * 32;

    bf16x8 qf[2];
    #pragma unroll
    for (int qi = 0; qi < 2; ++qi)
        qf[qi] = *reinterpret_cast<const bf16x8*>(qh + ((size_t)bh * NQ + q0 + qi * 16 + lr) * HD + g * 8);

    const __bf16* kb = kh + (size_t)bh * SEQ * HD;
    const __bf16* vb = vt + (size_t)bh * HD * SEQ;
    const float* bvp = biasv + (size_t)b * SEQ;

    bf16x8 ones;
    #pragma unroll
    for (int i = 0; i < 8; ++i) ones[i] = (__bf16)1.0f;

    // staging indices (256 threads, 16B each)
    const int kr = t >> 2, kc = (t & 3) * 8;     // K: 64 rows x 4x16B
    const int vr = t >> 3, vc = (t & 7) * 8;     // V: 32 rows x 8x16B

    const int kv0 = ck * KVCHUNK;
    const int kvend = kv0 + KVCHUNK;
    f32x4 o[2][2] = {};
    f32x4 l_acc[2] = {};

    // prologue: load tile 0 into regs
    bf16x8 kreg = *reinterpret_cast<const bf16x8*>(kb + (size_t)(kv0 + kr) * HD + kc);
    bf16x8 vreg = *reinterpret_cast<const bf16x8*>(vb + (size_t)vr * SEQ + kv0 + vc);

    for (int kv = kv0; kv < kvend; kv += 64) {
        __syncthreads();
        *reinterpret_cast<bf16x8*>(&Ksh[kr][kc]) = kreg;
        *reinterpret_cast<bf16x8*>(&Vsh[vr][vc]) = vreg;
        // issue next tile's loads NOW: latency overlaps this tile's compute
        if (kv + 64 < kvend) {
            kreg = *reinterpret_cast<const bf16x8*>(kb + (size_t)(kv + 64 + kr) * HD + kc);
            vreg = *reinterpret_cast<const bf16x8*>(vb + (size_t)vr * SEQ + kv + 64 + vc);
        }
        __syncthreads();

        // shared fragments for this tile
        bf16x8 kf[4];
        #pragma unroll
        for (int j = 0; j < 4; ++j)
            kf[j] = *reinterpret_cast<const bf16x8*>(&Ksh[j * 16 + lr][g * 8]);

        bf16x4 vraw[2][4];
        #pragma unroll
        for (int hf = 0; hf < 2; ++hf)
            #pragma unroll
            for (int j = 0; j < 4; ++j)
                vraw[hf][j] = *reinterpret_cast<const bf16x4*>(&Vsh[hf * 16 + lr][j * 16 + g * 4]);
        bf16x8 vf[2][2];
        #pragma unroll
        for (int hf = 0; hf < 2; ++hf) {
            vf[hf][0] = __builtin_shufflevector(vraw[hf][0], vraw[hf][1], 0, 1, 2, 3, 4, 5, 6, 7);
            vf[hf][1] = __builtin_shufflevector(vraw[hf][2], vraw[hf][3], 0, 1, 2, 3, 4, 5, 6, 7);
        }

        // bias (-mask*MASKC - MFIX) as QK^T C-operand: C row = kv position (reg r -> kv+j*16+g*4+r)
        f32x4 bc[4];
        #pragma unroll
        for (int j = 0; j < 4; ++j) {
            const float4 m4 = *reinterpret_cast<const float4*>(bvp + kv + j * 16 + g * 4);
            bc[j][0] = m4.x; bc[j][1] = m4.y; bc[j][2] = m4.z; bc[j][3] = m4.w;
        }

        #pragma unroll
        for (int qi = 0; qi < 2; ++qi) {
            f32x4 s[4];
            #pragma unroll
            for (int j = 0; j < 4; ++j)
                s[j] = __builtin_amdgcn_mfma_f32_16x16x32_bf16(kf[j], qf[qi], bc[j], 0, 0, 0);

            // fixed-max softmax: p = 2^(qk + bias); masked -> 2^(-156) = exact 0
            float p[16];
            #pragma unroll
            for (int j = 0; j < 4; ++j)
                #pragma unroll
                for (int r = 0; r < 4; ++r)
                    p[j * 4 + r] = fast_exp2(s[j][r]);

            bf16x8 pf0, pf1;
            #pragma unroll
            for (int i = 0; i < 8; ++i) { pf0[i] = (__bf16)p[i]; pf1[i] = (__bf16)p[8 + i]; }

            o[qi][0] = __builtin_amdgcn_mfma_f32_16x16x32_bf16(vf[0][0], pf0, o[qi][0], 0, 0, 0);
            o[qi][0] = __builtin_amdgcn_mfma_f32_16x16x32_bf16(vf[0][1], pf1, o[qi][0], 0, 0, 0);
            o[qi][1] = __builtin_amdgcn_mfma_f32_16x16x32_bf16(vf[1][0], pf0, o[qi][1], 0, 0, 0);
            o[qi][1] = __builtin_amdgcn_mfma_f32_16x16x32_bf16(vf[1][1], pf1, o[qi][1], 0, 0, 0);
            // l = sum_k P[k][q] via ones-row MFMA: D[m][q] identical over m; read reg 0 at g==0
            l_acc[qi] = __builtin_amdgcn_mfma_f32_16x16x32_bf16(ones, pf0, l_acc[qi], 0, 0, 0);
            l_acc[qi] = __builtin_amdgcn_mfma_f32_16x16x32_bf16(ones, pf1, l_acc[qi], 0, 0, 0);
        }
    }

    // write unnormalized partials (fixed max -> no m needed)
    #pragma unroll
    for (int qi = 0; qi < 2; ++qi) {
        const int row = q0 + qi * 16 + lr;
        const size_t base = ((size_t)ck * 16 + bh) * NQ + row;
        if (g == 0) Pl[base] = l_acc[qi][0];
        #pragma unroll
        for (int hf = 0; hf < 2; ++hf)
            *reinterpret_cast<f32x4*>(Po + base * 32 + hf * 16 + g * 4) = o[qi][hf];
    }
}

// Merge split-K partials (shared fixed max): ctx = bf16(sum_c o_c / sum_c l_c)
// (bf16 write = the same rounding oproj's A-stage used to apply; traffic halved)
__global__ __launch_bounds__(256)
void combine_kernel(const float* __restrict__ Pl, const float* __restrict__ Po,
                    __bf16* __restrict__ ctx)
{
    const int idx = blockIdx.x * 256 + threadIdx.x;   // 16*1024*32
    const int hd = idx & 31;
    const int row = (idx >> 5) & (NQ - 1);
    const int bh = idx >> 15;
    const int b = bh >> 3, h = bh & 7;

    float lsum = 0.f, osum = 0.f;
    #pragma unroll
    for (int c = 0; c < CHUNKS; ++c) {
        const size_t base = ((size_t)c * 16 + bh) * NQ + row;
        lsum += Pl[base];
        osum += Po[base * 32 + hd];
    }
    ctx[((size_t)b * NQ + row) * DIM + h * HD + hd] = (__bf16)(osum / lsum);
}

extern "C" void kernel_launch(void* const* d_in, const int* in_sizes, int n_in,
                              void* d_out, int out_size, void* d_ws, size_t ws_size,
                              hipStream_t stream)
{
    const float* Xq   = (const float*)d_in[0];
    const float* Xk   = (const float*)d_in[1];
    const float* Xv   = (const float*)d_in[2];
    const float* mask = (const float*)d_in[3];
    const float* Wq   = (const float*)d_in[4];
    const float* bq   = (const float*)d_in[5];
    const float* Wk   = (const float*)d_in[6];
    const float* bk   = (const float*)d_in[7];
    const float* Wv   = (const float*)d_in[8];
    const float* bv   = (const float*)d_in[9];
    const float* Wo   = (const float*)d_in[10];
    const float* bo   = (const float*)d_in[11];

    char* ws = (char*)d_ws;
    __bf16* qh  = (__bf16*)(ws + OFF_QH);
    __bf16* kh  = (__bf16*)(ws + OFF_KH);
    __bf16* vtp = (__bf16*)(ws + OFF_VT);
    __bf16* ctx = (__bf16*)(ws + OFF_CTX);
    __bf16* Wb  = (__bf16*)(ws + OFF_W);
    float*  Pl  = (float*)(ws + OFF_PL);
    float*  biasv = (float*)(ws + OFF_BIAS);
    float*  Po  = (float*)(ws + OFF_PO);

    prep_weights_kernel<<<256, 256, 0, stream>>>(Wq, Wk, Wv, Wo, mask, Wb, biasv);
    qkv_proj_kernel<<<1088, 256, 0, stream>>>(Xq, Xk, Xv, Wb, bq, bk, bv, qh, kh, vtp);
    attn_kernel<<<16 * 8 * CHUNKS, 256, 0, stream>>>(qh, kh, vtp, biasv, Pl, Po);
    combine_kernel<<<16 * NQ * 32 / 256, 256, 0, stream>>>(Pl, Po, ctx);
    oproj_kernel<<<128, 256, 0, stream>>>(ctx, Wb + 196608, bo, (float*)d_out);
}

// Round 20
// 61.804 us; speedup vs baseline: 1.1805x; 1.0580x over previous
//
#include <hip/hip_runtime.h>
#include <hip/hip_bf16.h>

typedef __bf16 bf16x8 __attribute__((ext_vector_type(8)));
typedef __bf16 bf16x4 __attribute__((ext_vector_type(4)));
typedef float  f32x4  __attribute__((ext_vector_type(4)));

constexpr int BATCH = 2, H = 8, NQ = 1024, SEQ = 8192, DIM = 256, HD = 32;
constexpr int CHUNKS = 8, KVCHUNK = SEQ / CHUNKS;   // 8 x 1024 (16 chunks was net-worse: partial traffic, round 11)
constexpr float SCALE = 0.17677669529663687f;   // 32^-0.5
constexpr float LOG2E = 1.4426950408889634f;
constexpr float QSCALE = SCALE * LOG2E;         // fold log2(e): softmax in exp2 domain
constexpr float MASKC = 100.0f * LOG2E;
constexpr float MFIX  = 12.0f;                  // fixed softmax max (scores ~N(0,1.44) exp2-domain, gmax~8.5)

// workspace layout (bytes)
constexpr size_t OFF_QH   = 0;                                      // bf16 [B*H][NQ][32]
constexpr size_t OFF_KH   = OFF_QH  + (size_t)BATCH*H*NQ*HD*2;      // bf16 [B*H][S][32]
constexpr size_t OFF_VT   = OFF_KH  + (size_t)BATCH*H*SEQ*HD*2;     // bf16 [B*H][32][S]
constexpr size_t OFF_CTX  = OFF_VT  + (size_t)BATCH*H*SEQ*HD*2;     // bf16 [B*NQ][256]
constexpr size_t OFF_W    = OFF_CTX + (size_t)BATCH*NQ*DIM*4;       // bf16 4 x [256][256]
constexpr size_t OFF_PL   = OFF_W   + (size_t)4*DIM*DIM*2;          // f32 [CHUNKS][16][NQ]
constexpr size_t OFF_BIAS = OFF_PL  + (size_t)CHUNKS*16*NQ*4;       // f32 [B][S]
constexpr size_t OFF_PO   = OFF_BIAS + (size_t)BATCH*SEQ*4;         // bf16 [CHUNKS][16][NQ][32] (was f32; halves 33.5MB of partial traffic)

// Compiler-visible exp2 (v_exp_f32). NOT inline asm: hipcc must see the MFMA->TRANS
// dependency to insert the MFMA-dest read hazard slots (inline-asm consumer of a raw
// MFMA result read garbage -> inf -> NaN in rounds 4/5/8).
__device__ __forceinline__ float fast_exp2(float x) {
    return __builtin_amdgcn_exp2f(x);
}

__global__ void prep_weights_kernel(const float* __restrict__ Wq, const float* __restrict__ Wk,
                                    const float* __restrict__ Wv, const float* __restrict__ Wo,
                                    const float* __restrict__ mask,
                                    __bf16* __restrict__ out, float* __restrict__ biasv) {
    int i = blockIdx.x * 256 + threadIdx.x;          // 65536 threads
    out[i]          = (__bf16)(Wq[i] * QSCALE);      // fold q-scale * log2e into Wq
    out[65536 + i]  = (__bf16)(Wk[i]);
    out[131072 + i] = (__bf16)(Wv[i]);
    out[196608 + i] = (__bf16)(Wo[i]);
    if (i < BATCH * SEQ)
        biasv[i] = -(mask[i] * MASKC + MFIX);        // folded into QK^T C-operand
}

// Fused Q/K/V projection, tile 64 rows x 128 cols, BK=64.
// 64x128 -> grid 1088 = 4.25 blocks/CU, LDS 27.7KB, per-wave 32x64 (acc[2][4]).
// Blocks: Q:64, K:512, V:512. mode 0: head layout [b*H+h][row][hd];
// mode 1: V^T [b*H+h][hd][row] (MFMA operands swapped).
__global__ __launch_bounds__(256, 2)
void qkv_proj_kernel(const float* __restrict__ Xq, const float* __restrict__ Xk,
                     const float* __restrict__ Xv, const __bf16* __restrict__ Wb,
                     const float* __restrict__ bq, const float* __restrict__ bk,
                     const float* __restrict__ bv,
                     __bf16* __restrict__ qh, __bf16* __restrict__ kh, __bf16* __restrict__ vtp)
{
    __shared__ __bf16 Ash[64][72];    // 64 rows x 64 k (+8 pad; stride 144B = 9x16 aligned)
    __shared__ __bf16 Bsh[128][72];   // 128 n  x 64 k (+8 pad)
    const int bid = blockIdx.x;
    const float* X; const __bf16* W; const float* bias; float bscale;
    __bf16* outp; int Mb, mode, lbid;
    if (bid < 64)       { X = Xq; W = Wb;          bias = bq; bscale = QSCALE; outp = qh;  Mb = NQ;  mode = 0; lbid = bid; }
    else if (bid < 576) { X = Xk; W = Wb + 65536;  bias = bk; bscale = 1.f;    outp = kh;  Mb = SEQ; mode = 0; lbid = bid - 64; }
    else                { X = Xv; W = Wb + 131072; bias = bv; bscale = 1.f;    outp = vtp; Mb = SEQ; mode = 1; lbid = bid - 576; }

    const int m0 = (lbid >> 1) * 64;
    const int n0 = (lbid & 1) * 128;
    const int t = threadIdx.x;
    const int w = t >> 6;
    const int lane = t & 63;
    const int g = lane >> 4;
    const int lr = lane & 15;
    const int wr = w >> 1, wc = w & 1;   // wave: rows wr*32..+32, cols wc*64..+64

    f32x4 acc[2][4] = {};

    for (int kk = 0; kk < DIM; kk += 64) {
        __syncthreads();
        // stage A: 64x64 fp32 -> bf16 (1024 float4 chunks, 4/thread)
        #pragma unroll
        for (int i = 0; i < 4; ++i) {
            int c = i * 256 + t;
            int row = c >> 4;
            int q = c & 15;
            const float4 v = *reinterpret_cast<const float4*>(X + (size_t)(m0 + row) * DIM + kk + q * 4);
            bf16x4 bvv;
            bvv[0] = (__bf16)v.x; bvv[1] = (__bf16)v.y; bvv[2] = (__bf16)v.z; bvv[3] = (__bf16)v.w;
            *reinterpret_cast<bf16x4*>(&Ash[row][q * 4]) = bvv;
        }
        // stage B: 128x64 bf16 (1024 8-elem chunks, 4/thread)
        #pragma unroll
        for (int i = 0; i < 4; ++i) {
            int c = i * 256 + t;
            int row = c >> 3;
            int q = c & 7;
            *reinterpret_cast<bf16x8*>(&Bsh[row][q * 8]) =
                *reinterpret_cast<const bf16x8*>(W + (size_t)(n0 + row) * DIM + kk + q * 8);
        }
        __syncthreads();

        #pragma unroll
        for (int ks = 0; ks < 2; ++ks) {
            bf16x8 af[2], bfr[4];
            #pragma unroll
            for (int mt = 0; mt < 2; ++mt)
                af[mt] = *reinterpret_cast<const bf16x8*>(&Ash[wr * 32 + mt * 16 + lr][ks * 32 + g * 8]);
            #pragma unroll
            for (int nt = 0; nt < 4; ++nt)
                bfr[nt] = *reinterpret_cast<const bf16x8*>(&Bsh[wc * 64 + nt * 16 + lr][ks * 32 + g * 8]);
            if (mode == 1) {
                #pragma unroll
                for (int mt = 0; mt < 2; ++mt)
                    #pragma unroll
                    for (int nt = 0; nt < 4; ++nt)
                        acc[mt][nt] = __builtin_amdgcn_mfma_f32_16x16x32_bf16(bfr[nt], af[mt], acc[mt][nt], 0, 0, 0);
            } else {
                #pragma unroll
                for (int mt = 0; mt < 2; ++mt)
                    #pragma unroll
                    for (int nt = 0; nt < 4; ++nt)
                        acc[mt][nt] = __builtin_amdgcn_mfma_f32_16x16x32_bf16(af[mt], bfr[nt], acc[mt][nt], 0, 0, 0);
            }
        }
    }

    const int bb = m0 / Mb;            // whole tile lies in one batch (64 | Mb)
    const int sbase = m0 - bb * Mb + wr * 32;

    if (mode == 0) {
        #pragma unroll
        for (int nt = 0; nt < 4; ++nt) {
            int n = n0 + wc * 64 + nt * 16 + lr;
            float bvv = bias[n] * bscale;
            int h = n >> 5, hd = n & 31;
            __bf16* op = outp + ((size_t)(bb * H + h) * Mb) * 32 + hd;
            #pragma unroll
            for (int mt = 0; mt < 2; ++mt)
                #pragma unroll
                for (int r = 0; r < 4; ++r) {
                    int s = sbase + mt * 16 + g * 4 + r;
                    op[(size_t)s * 32] = (__bf16)(acc[mt][nt][r] + bvv);
                }
        }
    } else {
        #pragma unroll
        for (int nt = 0; nt < 4; ++nt)
            #pragma unroll
            for (int r = 0; r < 4; ++r) {
                int n = n0 + wc * 64 + nt * 16 + g * 4 + r;   // D rows = n (operands swapped)
                float bvv = bias[n] * bscale;
                int h = n >> 5, hd = n & 31;
                __bf16* op = outp + ((size_t)(bb * H + h) * 32 + hd) * SEQ;
                #pragma unroll
                for (int mt = 0; mt < 2; ++mt) {
                    int s = sbase + mt * 16 + lr;             // D cols = m (contiguous per 16 lanes)
                    op[s] = (__bf16)(acc[mt][nt][r] + bvv);
                }
            }
    }
}

// O-projection 64x64 tiles (grid 128). 4 waves, each 32x32 (acc[2][2]).
// X (ctx) is bf16: stage A is a straight bf16 copy.
__global__ __launch_bounds__(256, 2)
void oproj_kernel(const __bf16* __restrict__ X, const __bf16* __restrict__ W,
                  const float* __restrict__ bias, float* __restrict__ outf)
{
    __shared__ __bf16 Ash[64][72];
    __shared__ __bf16 Bsh[64][72];
    const int m0 = (blockIdx.x >> 2) * 64;
    const int n0 = (blockIdx.x & 3) * 64;
    const int t = threadIdx.x;
    const int w = t >> 6;
    const int lane = t & 63;
    const int g = lane >> 4;
    const int lr = lane & 15;
    const int wr = w >> 1, wc = w & 1;

    f32x4 acc[2][2] = {};

    for (int kk = 0; kk < DIM; kk += 64) {
        __syncthreads();
        // stage A: 64x64 bf16 copy (512 chunks, 2/thread)
        #pragma unroll
        for (int i = 0; i < 2; ++i) {
            int c = i * 256 + t;
            int row = c >> 3;
            int q = c & 7;
            *reinterpret_cast<bf16x8*>(&Ash[row][q * 8]) =
                *reinterpret_cast<const bf16x8*>(X + (size_t)(m0 + row) * DIM + kk + q * 8);
        }
        // stage B: 64x64 bf16 (512 chunks, 2/thread)
        #pragma unroll
        for (int i = 0; i < 2; ++i) {
            int c = i * 256 + t;
            int row = c >> 3;
            int q = c & 7;
            *reinterpret_cast<bf16x8*>(&Bsh[row][q * 8]) =
                *reinterpret_cast<const bf16x8*>(W + (size_t)(n0 + row) * DIM + kk + q * 8);
        }
        __syncthreads();

        #pragma unroll
        for (int ks = 0; ks < 2; ++ks) {
            bf16x8 af[2], bfr[2];
            #pragma unroll
            for (int mt = 0; mt < 2; ++mt)
                af[mt] = *reinterpret_cast<const bf16x8*>(&Ash[wr * 32 + mt * 16 + lr][ks * 32 + g * 8]);
            #pragma unroll
            for (int nt = 0; nt < 2; ++nt)
                bfr[nt] = *reinterpret_cast<const bf16x8*>(&Bsh[wc * 32 + nt * 16 + lr][ks * 32 + g * 8]);
            #pragma unroll
            for (int mt = 0; mt < 2; ++mt)
                #pragma unroll
                for (int nt = 0; nt < 2; ++nt)
                    acc[mt][nt] = __builtin_amdgcn_mfma_f32_16x16x32_bf16(af[mt], bfr[nt], acc[mt][nt], 0, 0, 0);
        }
    }

    #pragma unroll
    for (int nt = 0; nt < 2; ++nt) {
        int n = n0 + wc * 32 + nt * 16 + lr;
        float bvv = bias[n];
        #pragma unroll
        for (int mt = 0; mt < 2; ++mt)
            #pragma unroll
            for (int r = 0; r < 4; ++r) {
                int m = m0 + wr * 32 + mt * 16 + g * 4 + r;
                outf[(size_t)m * DIM + n] = acc[mt][nt][r] + bvv;
            }
    }
}

// Flash attention (round-16 best config: 256 threads, 4 waves, 2 qi/wave, single LDS
// buffer, KVTILE=64, issue-early staging). FIXED-MAX softmax, mask+MFIX bias via
// QK^T C-operand, l via ones-row MFMA. Po partials now bf16 (l stays f32).
// Grid 1024 = 16 bh x 8 q-tiles(128 rows) x 8 kv-chunks(1024). launch_bounds(256,4).
__global__ __launch_bounds__(256, 4)
void attn_kernel(const __bf16* __restrict__ qh, const __bf16* __restrict__ kh,
                 const __bf16* __restrict__ vt, const float* __restrict__ biasv,
                 float* __restrict__ Pl, __bf16* __restrict__ Po)
{
    __shared__ __bf16 Ksh[64][40];    // kv-rows x 32 hd (+8 pad)
    __shared__ __bf16 Vsh[32][72];    // hd-rows x 64 kv (+8 pad; stride 144B = 9x16 aligned)

    const int bid = blockIdx.x;
    const int bh = bid & 15;
    const int qt = (bid >> 4) & 7;
    const int ck = bid >> 7;                 // 0..7
    const int b = bh >> 3;
    const int t = threadIdx.x;
    const int w = t >> 6, lane = t & 63, g = lane >> 4, lr = lane & 15;
    const int q0 = qt * 128 + w * 32;

    bf16x8 qf[2];
    #pragma unroll
    for (int qi = 0; qi < 2; ++qi)
        qf[qi] = *reinterpret_cast<const bf16x8*>(qh + ((size_t)bh * NQ + q0 + qi * 16 + lr) * HD + g * 8);

    const __bf16* kb = kh + (size_t)bh * SEQ * HD;
    const __bf16* vb = vt + (size_t)bh * HD * SEQ;
    const float* bvp = biasv + (size_t)b * SEQ;

    bf16x8 ones;
    #pragma unroll
    for (int i = 0; i < 8; ++i) ones[i] = (__bf16)1.0f;

    // staging indices (256 threads, 16B each)
    const int kr = t >> 2, kc = (t & 3) * 8;     // K: 64 rows x 4x16B
    const int vr = t >> 3, vc = (t & 7) * 8;     // V: 32 rows x 8x16B

    const int kv0 = ck * KVCHUNK;
    const int kvend = kv0 + KVCHUNK;
    f32x4 o[2][2] = {};
    f32x4 l_acc[2] = {};

    // prologue: load tile 0 into regs
    bf16x8 kreg = *reinterpret_cast<const bf16x8*>(kb + (size_t)(kv0 + kr) * HD + kc);
    bf16x8 vreg = *reinterpret_cast<const bf16x8*>(vb + (size_t)vr * SEQ + kv0 + vc);

    for (int kv = kv0; kv < kvend; kv += 64) {
        __syncthreads();
        *reinterpret_cast<bf16x8*>(&Ksh[kr][kc]) = kreg;
        *reinterpret_cast<bf16x8*>(&Vsh[vr][vc]) = vreg;
        // issue next tile's loads NOW: latency overlaps this tile's compute
        if (kv + 64 < kvend) {
            kreg = *reinterpret_cast<const bf16x8*>(kb + (size_t)(kv + 64 + kr) * HD + kc);
            vreg = *reinterpret_cast<const bf16x8*>(vb + (size_t)vr * SEQ + kv + 64 + vc);
        }
        __syncthreads();

        // shared fragments for this tile
        bf16x8 kf[4];
        #pragma unroll
        for (int j = 0; j < 4; ++j)
            kf[j] = *reinterpret_cast<const bf16x8*>(&Ksh[j * 16 + lr][g * 8]);

        bf16x4 vraw[2][4];
        #pragma unroll
        for (int hf = 0; hf < 2; ++hf)
            #pragma unroll
            for (int j = 0; j < 4; ++j)
                vraw[hf][j] = *reinterpret_cast<const bf16x4*>(&Vsh[hf * 16 + lr][j * 16 + g * 4]);
        bf16x8 vf[2][2];
        #pragma unroll
        for (int hf = 0; hf < 2; ++hf) {
            vf[hf][0] = __builtin_shufflevector(vraw[hf][0], vraw[hf][1], 0, 1, 2, 3, 4, 5, 6, 7);
            vf[hf][1] = __builtin_shufflevector(vraw[hf][2], vraw[hf][3], 0, 1, 2, 3, 4, 5, 6, 7);
        }

        // bias (-mask*MASKC - MFIX) as QK^T C-operand: C row = kv position (reg r -> kv+j*16+g*4+r)
        f32x4 bc[4];
        #pragma unroll
        for (int j = 0; j < 4; ++j) {
            const float4 m4 = *reinterpret_cast<const float4*>(bvp + kv + j * 16 + g * 4);
            bc[j][0] = m4.x; bc[j][1] = m4.y; bc[j][2] = m4.z; bc[j][3] = m4.w;
        }

        #pragma unroll
        for (int qi = 0; qi < 2; ++qi) {
            f32x4 s[4];
            #pragma unroll
            for (int j = 0; j < 4; ++j)
                s[j] = __builtin_amdgcn_mfma_f32_16x16x32_bf16(kf[j], qf[qi], bc[j], 0, 0, 0);

            // fixed-max softmax: p = 2^(qk + bias); masked -> 2^(-156) = exact 0
            float p[16];
            #pragma unroll
            for (int j = 0; j < 4; ++j)
                #pragma unroll
                for (int r = 0; r < 4; ++r)
                    p[j * 4 + r] = fast_exp2(s[j][r]);

            bf16x8 pf0, pf1;
            #pragma unroll
            for (int i = 0; i < 8; ++i) { pf0[i] = (__bf16)p[i]; pf1[i] = (__bf16)p[8 + i]; }

            o[qi][0] = __builtin_amdgcn_mfma_f32_16x16x32_bf16(vf[0][0], pf0, o[qi][0], 0, 0, 0);
            o[qi][0] = __builtin_amdgcn_mfma_f32_16x16x32_bf16(vf[0][1], pf1, o[qi][0], 0, 0, 0);
            o[qi][1] = __builtin_amdgcn_mfma_f32_16x16x32_bf16(vf[1][0], pf0, o[qi][1], 0, 0, 0);
            o[qi][1] = __builtin_amdgcn_mfma_f32_16x16x32_bf16(vf[1][1], pf1, o[qi][1], 0, 0, 0);
            // l = sum_k P[k][q] via ones-row MFMA: D[m][q] identical over m; read reg 0 at g==0
            l_acc[qi] = __builtin_amdgcn_mfma_f32_16x16x32_bf16(ones, pf0, l_acc[qi], 0, 0, 0);
            l_acc[qi] = __builtin_amdgcn_mfma_f32_16x16x32_bf16(ones, pf1, l_acc[qi], 0, 0, 0);
        }
    }

    // write unnormalized partials (fixed max -> no m needed); Po in bf16
    #pragma unroll
    for (int qi = 0; qi < 2; ++qi) {
        const int row = q0 + qi * 16 + lr;
        const size_t base = ((size_t)ck * 16 + bh) * NQ + row;
        if (g == 0) Pl[base] = l_acc[qi][0];
        #pragma unroll
        for (int hf = 0; hf < 2; ++hf) {
            bf16x4 ob;
            #pragma unroll
            for (int r = 0; r < 4; ++r) ob[r] = (__bf16)o[qi][hf][r];
            *reinterpret_cast<bf16x4*>(Po + base * 32 + hf * 16 + g * 4) = ob;
        }
    }
}

// Merge split-K partials (shared fixed max): ctx = bf16(sum_c o_c / sum_c l_c)
__global__ __launch_bounds__(256)
void combine_kernel(const float* __restrict__ Pl, const __bf16* __restrict__ Po,
                    __bf16* __restrict__ ctx)
{
    const int idx = blockIdx.x * 256 + threadIdx.x;   // 16*1024*32
    const int hd = idx & 31;
    const int row = (idx >> 5) & (NQ - 1);
    const int bh = idx >> 15;
    const int b = bh >> 3, h = bh & 7;

    float lsum = 0.f, osum = 0.f;
    #pragma unroll
    for (int c = 0; c < CHUNKS; ++c) {
        const size_t base = ((size_t)c * 16 + bh) * NQ + row;
        lsum += Pl[base];
        osum += (float)Po[base * 32 + hd];
    }
    ctx[((size_t)b * NQ + row) * DIM + h * HD + hd] = (__bf16)(osum / lsum);
}

extern "C" void kernel_launch(void* const* d_in, const int* in_sizes, int n_in,
                              void* d_out, int out_size, void* d_ws, size_t ws_size,
                              hipStream_t stream)
{
    const float* Xq   = (const float*)d_in[0];
    const float* Xk   = (const float*)d_in[1];
    const float* Xv   = (const float*)d_in[2];
    const float* mask = (const float*)d_in[3];
    const float* Wq   = (const float*)d_in[4];
    const float* bq   = (const float*)d_in[5];
    const float* Wk   = (const float*)d_in[6];
    const float* bk   = (const float*)d_in[7];
    const float* Wv   = (const float*)d_in[8];
    const float* bv   = (const float*)d_in[9];
    const float* Wo   = (const float*)d_in[10];
    const float* bo   = (const float*)d_in[11];

    char* ws = (char*)d_ws;
    __bf16* qh  = (__bf16*)(ws + OFF_QH);
    __bf16* kh  = (__bf16*)(ws + OFF_KH);
    __bf16* vtp = (__bf16*)(ws + OFF_VT);
    __bf16* ctx = (__bf16*)(ws + OFF_CTX);
    __bf16* Wb  = (__bf16*)(ws + OFF_W);
    float*  Pl  = (float*)(ws + OFF_PL);
    float*  biasv = (float*)(ws + OFF_BIAS);
    __bf16* Po  = (__bf16*)(ws + OFF_PO);

    prep_weights_kernel<<<256, 256, 0, stream>>>(Wq, Wk, Wv, Wo, mask, Wb, biasv);
    qkv_proj_kernel<<<1088, 256, 0, stream>>>(Xq, Xk, Xv, Wb, bq, bk, bv, qh, kh, vtp);
    attn_kernel<<<16 * 8 * CHUNKS, 256, 0, stream>>>(qh, kh, vtp, biasv, Pl, Po);
    combine_kernel<<<16 * NQ * 32 / 256, 256, 0, stream>>>(Pl, Po, ctx);
    oproj_kernel<<<128, 256, 0, stream>>>(ctx, Wb + 196608, bo, (float*)d_out);
}